// Round 1
// baseline (4039.405 us; speedup 1.0000x reference)
//
#include <hip/hip_runtime.h>

#define NATOMS 100000
#define NPAIRS 3200000
// F_ATOM=75, F_PAIR=14, H=50, F_OUT=50

// K1: per-atom precompute:
//   AA  = relu(af @ W_AA.T + b_AA)              [NATOMS,50]
//   X1' = af @ W_AP[:, :75].T + b_AP            (stored XA[a][0:50])
//   X2  = af @ W_AP[:, 75:].T                   (stored XA[a][50:100])
__global__ __launch_bounds__(256) void k_atom_pre(
    const float* __restrict__ af,
    const float* __restrict__ W_AA, const float* __restrict__ b_AA,
    const float* __restrict__ W_AP, const float* __restrict__ b_AP,
    float* __restrict__ AA, float* __restrict__ XA)
{
    int a = blockIdx.x * 256 + threadIdx.x;
    if (a >= NATOMS) return;
    const float* ar = af + (size_t)a * 75;
    float x[75];
#pragma unroll
    for (int k = 0; k < 75; ++k) x[k] = ar[k];

    float* aout = AA + (size_t)a * 50;
#pragma unroll
    for (int jc = 0; jc < 50; jc += 25) {
        float acc[25];
#pragma unroll
        for (int j = 0; j < 25; ++j) acc[j] = b_AA[jc + j];
#pragma unroll
        for (int k = 0; k < 75; ++k) {
#pragma unroll
            for (int j = 0; j < 25; ++j)
                acc[j] = fmaf(x[k], W_AA[(jc + j) * 75 + k], acc[j]);
        }
#pragma unroll
        for (int j = 0; j < 25; ++j) aout[jc + j] = fmaxf(acc[j], 0.0f);
    }

    float* xout = XA + (size_t)a * 100;
#pragma unroll
    for (int jc = 0; jc < 50; jc += 25) {
        float a1[25], a2[25];
#pragma unroll
        for (int j = 0; j < 25; ++j) { a1[j] = b_AP[jc + j]; a2[j] = 0.0f; }
#pragma unroll
        for (int k = 0; k < 75; ++k) {
#pragma unroll
            for (int j = 0; j < 25; ++j) {
                a1[j] = fmaf(x[k], W_AP[(jc + j) * 150 + k],      a1[j]);
                a2[j] = fmaf(x[k], W_AP[(jc + j) * 150 + 75 + k], a2[j]);
            }
        }
#pragma unroll
        for (int j = 0; j < 25; ++j) {
            xout[jc + j]      = a1[j];
            xout[50 + jc + j] = a2[j];
        }
    }
}

// K2: per-pair fused kernel. One thread per pair, 256 pairs/block.
//   PA = relu(pf@W_PA.T+b_PA)  -> LDS -> per-block run reduction -> atomicAdd PAsum
//   PP = relu(pf@W_PP.T+b_PP)
//   S  = relu(X1'[i]+X2[j]) + relu(X1'[j]+X2[i])
//   P  = relu(S@WP1.T + PP@WP2.T + b_P)   (WP1=W_P[:,:50], WP2=W_P[:,50:])
__global__ __launch_bounds__(256) void k_pair(
    const float* __restrict__ pf,
    const int* __restrict__ psplit,
    const int* __restrict__ a2p,
    const float* __restrict__ W_PA, const float* __restrict__ b_PA,
    const float* __restrict__ W_PP, const float* __restrict__ b_PP,
    const float* __restrict__ W_P,  const float* __restrict__ b_P,
    const float* __restrict__ XA,
    float* __restrict__ PAsum,
    float* __restrict__ Pout)
{
    __shared__ float pa_lds[256 * 52];   // pad 50->52 (16B-aligned rows)
    __shared__ int   ps_lds[256];
    __shared__ int   head_list[256];
    __shared__ int   nheads;

    const int t = threadIdx.x;
    const int p = blockIdx.x * 256 + t;  // NPAIRS == 12500*256 exactly, no guard
    if (t == 0) nheads = 0;

    const float* pr = pf + (size_t)p * 14;
    float x[14];
#pragma unroll
    for (int k = 0; k < 14; ++k) x[k] = pr[k];
    ps_lds[t] = psplit[p];

    // PA -> LDS (relu'd), registers freed after
    {
        float pa[50];
#pragma unroll
        for (int j = 0; j < 50; ++j) pa[j] = b_PA[j];
#pragma unroll
        for (int k = 0; k < 14; ++k) {
#pragma unroll
            for (int j = 0; j < 50; ++j)
                pa[j] = fmaf(x[k], W_PA[j * 14 + k], pa[j]);
        }
#pragma unroll
        for (int j = 0; j < 50; ++j) pa_lds[t * 52 + j] = fmaxf(pa[j], 0.0f);
    }

    // PP (kept in registers)
    float pp[50];
#pragma unroll
    for (int j = 0; j < 50; ++j) pp[j] = b_PP[j];
#pragma unroll
    for (int k = 0; k < 14; ++k) {
#pragma unroll
        for (int j = 0; j < 50; ++j)
            pp[j] = fmaf(x[k], W_PP[j * 14 + k], pp[j]);
    }
#pragma unroll
    for (int j = 0; j < 50; ++j) pp[j] = fmaxf(pp[j], 0.0f);

    // S via gathered per-atom precompute
    const int i0 = a2p[(size_t)p * 2 + 0];
    const int i1 = a2p[(size_t)p * 2 + 1];
    const float* xi = XA + (size_t)i0 * 100;
    const float* xj = XA + (size_t)i1 * 100;
    float s[50];
#pragma unroll
    for (int f = 0; f < 50; ++f)
        s[f] = fmaxf(xi[f] + xj[50 + f], 0.0f) + fmaxf(xj[f] + xi[50 + f], 0.0f);

    // P output
    float* po = Pout + (size_t)p * 50;
#pragma unroll
    for (int oc = 0; oc < 50; oc += 25) {
        float acc[25];
#pragma unroll
        for (int o = 0; o < 25; ++o) acc[o] = b_P[oc + o];
#pragma unroll
        for (int f = 0; f < 50; ++f) {
#pragma unroll
            for (int o = 0; o < 25; ++o)
                acc[o] = fmaf(s[f], W_P[(oc + o) * 100 + f], acc[o]);
        }
#pragma unroll
        for (int f = 0; f < 50; ++f) {
#pragma unroll
            for (int o = 0; o < 25; ++o)
                acc[o] = fmaf(pp[f], W_P[(oc + o) * 100 + 50 + f], acc[o]);
        }
#pragma unroll
        for (int o = 0; o < 25; ++o) po[oc + o] = fmaxf(acc[o], 0.0f);
    }

    // segment-sum of PA: pair_split sorted -> runs within block; one atomic per (run,f)
    __syncthreads();
    bool head = (t == 0) || (ps_lds[t] != ps_lds[t - 1]);
    if (head) {
        int idx = atomicAdd(&nheads, 1);
        head_list[idx] = t;
    }
    __syncthreads();

    const int nh = nheads;
    for (int w = t; w < nh * 50; w += 256) {
        const int r0  = head_list[w / 50];
        const int f   = w % 50;
        const int seg = ps_lds[r0];
        float acc = 0.0f;
        int rr = r0;
        do {
            acc += pa_lds[rr * 52 + f];
            ++rr;
        } while (rr < 256 && ps_lds[rr] == seg);
        atomicAdd(&PAsum[(size_t)seg * 50 + f], acc);
    }
}

// K3: A = relu(concat(AA, PAsum) @ W_A.T + b_A)
__global__ __launch_bounds__(256) void k_atom_final(
    const float* __restrict__ AA, const float* __restrict__ PAsum,
    const float* __restrict__ W_A, const float* __restrict__ b_A,
    float* __restrict__ Aout)
{
    int a = blockIdx.x * 256 + threadIdx.x;
    if (a >= NATOMS) return;
    float v[100];
    const float* p1 = AA + (size_t)a * 50;
    const float* p2 = PAsum + (size_t)a * 50;
#pragma unroll
    for (int f = 0; f < 50; ++f) v[f] = p1[f];
#pragma unroll
    for (int f = 0; f < 50; ++f) v[50 + f] = p2[f];
    float* ao = Aout + (size_t)a * 50;
#pragma unroll
    for (int oc = 0; oc < 50; oc += 25) {
        float acc[25];
#pragma unroll
        for (int o = 0; o < 25; ++o) acc[o] = b_A[oc + o];
#pragma unroll
        for (int f = 0; f < 100; ++f) {
#pragma unroll
            for (int o = 0; o < 25; ++o)
                acc[o] = fmaf(v[f], W_A[(oc + o) * 100 + f], acc[o]);
        }
#pragma unroll
        for (int o = 0; o < 25; ++o) ao[oc + o] = fmaxf(acc[o], 0.0f);
    }
}

extern "C" void kernel_launch(void* const* d_in, const int* in_sizes, int n_in,
                              void* d_out, int out_size, void* d_ws, size_t ws_size,
                              hipStream_t stream)
{
    const float* atom_features = (const float*)d_in[0];
    const float* pair_features = (const float*)d_in[1];
    const int*   pair_split    = (const int*)d_in[2];
    const int*   atom_to_pair  = (const int*)d_in[3];
    const float* W_AA = (const float*)d_in[4];
    const float* b_AA = (const float*)d_in[5];
    const float* W_PA = (const float*)d_in[6];
    const float* b_PA = (const float*)d_in[7];
    const float* W_A  = (const float*)d_in[8];
    const float* b_A  = (const float*)d_in[9];
    const float* W_AP = (const float*)d_in[10];
    const float* b_AP = (const float*)d_in[11];
    const float* W_PP = (const float*)d_in[12];
    const float* b_PP = (const float*)d_in[13];
    const float* W_P  = (const float*)d_in[14];
    const float* b_P  = (const float*)d_in[15];

    float* out   = (float*)d_out;
    float* A_out = out;                              // [NATOMS,50]
    float* P_out = out + (size_t)NATOMS * 50;        // [NPAIRS,50]

    float* AA    = (float*)d_ws;                     // 5,000,000 f32
    float* XA    = AA + (size_t)NATOMS * 50;         // 10,000,000 f32
    float* PAsum = XA + (size_t)NATOMS * 100;        // 5,000,000 f32

    hipMemsetAsync(PAsum, 0, (size_t)NATOMS * 50 * sizeof(float), stream);

    k_atom_pre<<<(NATOMS + 255) / 256, 256, 0, stream>>>(
        atom_features, W_AA, b_AA, W_AP, b_AP, AA, XA);

    k_pair<<<NPAIRS / 256, 256, 0, stream>>>(
        pair_features, pair_split, atom_to_pair,
        W_PA, b_PA, W_PP, b_PP, W_P, b_P,
        XA, PAsum, P_out);

    k_atom_final<<<(NATOMS + 255) / 256, 256, 0, stream>>>(
        AA, PAsum, W_A, b_A, A_out);
}